// Round 2
// baseline (187.934 us; speedup 1.0000x reference)
//
#include <hip/hip_runtime.h>

// RoIAlign: features (B=8, C=512, H=60, W=80) fp32, rois (N=1024,7) fp32
// out (N, C, 7, 7) fp32.
// R5 = R4 with compile fix: __builtin_nontemporal_store requires a clang
// ext_vector_type, not HIP's float4 class. No functional change.
// R4 design: channel-last transpose prepass. R3's main loop did 4 scattered
// scalar loads per output (lanes = bins within a channel plane) -> ~14 L1
// line touches per wave-load instruction, 4x redundant; vector-memory pipe
// bound (~200 us) despite HBM floor of ~29 us. R4 transposes features to
// (B, H, W, C) in d_ws (one streaming kernel, exact 64x64 tiles), then maps
// lanes = channels in the main kernel: every corner load is a dense 512 B
// wave read. Outputs are LDS-transposed (s_t[128][49], stride 49 odd ->
// conflict-free) so stores remain coalesced nontemporal float4.
// Keeps R3's XCD<->batch perm affinity + cs channel-phasing (per-XCD L2
// footprint 60*80*128*4 = 2.4 MB < 4 MB). Falls back to R3 path if ws_size
// < 78.65 MB.

typedef float floatx4 __attribute__((ext_vector_type(4)));

constexpr int   Bb = 8;
constexpr int   Cc = 512;
constexpr int   Hh = 60;
constexpr int   Ww = 80;
constexpr int   HW = Hh * Ww;            // 4800
constexpr int   Nn = 1024;
constexpr int   AH = 7;
constexpr int   AW = 7;
constexpr int   NB = AH * AW;            // 49 bins
constexpr int   CSPLIT = 4;              // channel phases
constexpr int   CPB = Cc / CSPLIT;       // 128 channels per block
constexpr int   OUT_PER_BLK = CPB * NB;  // 6272
constexpr int   QUOTA = Nn / Bb;         // 128 slots per batch residue class
constexpr float SCALE = 0.125f;
constexpr int   PXT = HW / 64;           // 75 pixel tiles (exact)
constexpr int   TBLKS = PXT * (Cc / 64) * Bb;  // 75*8*8 = 4800 transpose blocks

// ---- prepass: blocks 0..TBLKS-1 transpose feats (B,C,HW)->(B,HW,C);
//      block TBLKS builds perm so slot j hosts a ROI of batch j%8.
__global__ __launch_bounds__(256) void prep_kernel(
    const float* __restrict__ feats, const float* __restrict__ rois,
    float* __restrict__ ft, int* __restrict__ perm)
{
    const int tid = threadIdx.x;
    if (blockIdx.x == TBLKS) {
        __shared__ int cnt[Bb];
        __shared__ int ovf[Nn];
        __shared__ int novf;
        __shared__ int ntake;
        if (tid < Bb) cnt[tid] = 0;
        if (tid == 0) { novf = 0; ntake = 0; }
        for (int j = tid; j < Nn; j += 256) perm[j] = -1;
        __syncthreads();
        for (int r = tid; r < Nn; r += 256) {
            const int b = (int)rois[r * 7];
            const int pos = atomicAdd(&cnt[b], 1);
            if (pos < QUOTA) perm[b + Bb * pos] = r;
            else             ovf[atomicAdd(&novf, 1)] = r;
        }
        __syncthreads();
        for (int j = tid; j < Nn; j += 256) {
            if (perm[j] < 0) perm[j] = ovf[atomicAdd(&ntake, 1)];
        }
        return;
    }

    __shared__ float tile[64][65];       // +1 pad: column reads conflict-free
    const int bid = blockIdx.x;
    const int pb  = bid % PXT;           // pixel tile 0..74
    const int t   = bid / PXT;           // 0..63
    const int cb  = t & 7;               // channel tile 0..7
    const int b   = t >> 3;              // batch 0..7

    const float* src = feats + ((size_t)(b * Cc + cb * 64)) * HW + pb * 64;
    const int px  = tid & 63;
    const int ch4 = tid >> 6;            // 0..3
    #pragma unroll
    for (int i = 0; i < 16; ++i)
        tile[ch4 + 4 * i][px] = src[(ch4 + 4 * i) * HW + px];
    __syncthreads();
    float* dst = ft + ((size_t)(b * HW + pb * 64)) * Cc + cb * 64;
    const int c2 = tid & 63;
    const int p4 = tid >> 6;             // 0..3
    #pragma unroll
    for (int i = 0; i < 16; ++i)
        dst[(p4 + 4 * i) * Cc + c2] = tile[c2][p4 + 4 * i];
}

// ---- main: ft is (B, HW, C); lanes = channels -> all corner loads dense.
__global__ __launch_bounds__(256) void roialign_t_kernel(
    const float* __restrict__ ft,
    const float* __restrict__ rois,
    const int* __restrict__ perm,
    float* __restrict__ out)
{
    __shared__ int4 s_par[NB];           // {pix = hi*W+wi, hr, wr, msk}
    __shared__ int  s_pix;               // b * HW
    __shared__ __align__(16) float s_t[CPB][NB];  // 25088 B transpose buffer

    const int slot = blockIdx.x & (Nn - 1);
    const int cs   = blockIdx.x >> 10;   // 0..CSPLIT-1
    const int n    = perm[slot];
    const int tid  = threadIdx.x;
    const float* rp = rois + n * 7;

    if (tid < NB) {
        const float x1 = rp[2] * SCALE, y1 = rp[3] * SCALE;
        const float x2 = rp[4] * SCALE, y2 = rp[5] * SCALE;
        const float bin_h = fmaxf(y2 - y1, 0.0f) * (1.0f / (AH - 1));
        const float bin_w = fmaxf(x2 - x1, 0.0f) * (1.0f / (AW - 1));
        const int i = tid / AW;
        const int j = tid - i * AW;
        const float h = y1 + (float)i * bin_h;
        const float w = x1 + (float)j * bin_w;
        // reference: hstart = min(floor(h), H-2); hr = h - hstart (may be >1)
        const float hs = fminf(floorf(h), (float)(Hh - 2));
        const float ws = fminf(floorf(w), (float)(Ww - 2));
        const int hi = (int)fminf(fmaxf(hs, 0.0f), (float)(Hh - 2));
        const int wi = (int)fminf(fmaxf(ws, 0.0f), (float)(Ww - 2));
        const bool valid = (h >= 0.0f) && (h < (float)Hh) &&
                           (w >= 0.0f) && (w < (float)Ww);
        int4 pr;
        pr.x = hi * Ww + wi;
        pr.y = __float_as_int(h - hs);
        pr.z = __float_as_int(w - ws);
        pr.w = __float_as_int(valid ? 1.0f : 0.0f);
        s_par[tid] = pr;
        if (tid == 0) s_pix = (int)rp[0] * HW;
    }
    __syncthreads();

    const int cl   = tid & (CPB - 1);    // channel lane 0..127
    const int half = tid >> 7;           // 0/1: even/odd bins
    const float* fb = ft + (size_t)s_pix * Cc + cs * CPB + cl;

    #pragma unroll 4
    for (int r = half; r < NB; r += 2) {
        const int4 pr = s_par[r];        // wave-uniform broadcast
        const float* p = fb + (size_t)pr.x * Cc;
        const float v00 = p[0];
        const float v01 = p[Cc];
        const float v10 = p[Ww * Cc];
        const float v11 = p[Ww * Cc + Cc];
        const float hr  = __int_as_float(pr.y);
        const float wr  = __int_as_float(pr.z);
        const float msk = __int_as_float(pr.w);
        const float top = v00 + (v01 - v00) * wr;
        const float bot = v10 + (v11 - v10) * wr;
        s_t[cl][r] = (top + (bot - top) * hr) * msk;   // stride 49: no conflicts
    }
    __syncthreads();

    // coalesced store: s_t flattened IS the (c, bin) output order
    const float* st = &s_t[0][0];
    float* ob = out + (size_t)n * (Cc * NB) + cs * OUT_PER_BLK;
    for (int q = tid; q < OUT_PER_BLK / 4; q += 256) {
        const floatx4 v = *reinterpret_cast<const floatx4*>(st + 4 * q);
        __builtin_nontemporal_store(v, reinterpret_cast<floatx4*>(ob) + q);
    }
}

// ================= R3 fallback (workspace too small) =====================
__global__ __launch_bounds__(256) void roi_perm_kernel(
    const float* __restrict__ rois, int* __restrict__ perm)
{
    __shared__ int cnt[Bb];
    __shared__ int ovf[Nn];
    __shared__ int novf;
    __shared__ int ntake;
    const int tid = threadIdx.x;
    if (tid < Bb) cnt[tid] = 0;
    if (tid == 0) { novf = 0; ntake = 0; }
    for (int j = tid; j < Nn; j += 256) perm[j] = -1;
    __syncthreads();
    for (int r = tid; r < Nn; r += 256) {
        const int b = (int)rois[r * 7];
        const int pos = atomicAdd(&cnt[b], 1);
        if (pos < QUOTA) perm[b + Bb * pos] = r;
        else             ovf[atomicAdd(&novf, 1)] = r;
    }
    __syncthreads();
    for (int j = tid; j < Nn; j += 256) {
        if (perm[j] < 0) perm[j] = ovf[atomicAdd(&ntake, 1)];
    }
}

__global__ __launch_bounds__(256) void roialign_kernel(
    const float* __restrict__ feats,
    const float* __restrict__ rois,
    const int* __restrict__ perm,
    float* __restrict__ out)
{
    __shared__ int4 s_par[NB];
    __shared__ int  s_fbase;

    const int slot = blockIdx.x & (Nn - 1);
    const int cs   = blockIdx.x >> 10;
    const int n    = perm[slot];
    const int tid  = threadIdx.x;
    const float* rp = rois + n * 7;

    if (tid < NB) {
        const float x1 = rp[2] * SCALE, y1 = rp[3] * SCALE;
        const float x2 = rp[4] * SCALE, y2 = rp[5] * SCALE;
        const float bin_h = fmaxf(y2 - y1, 0.0f) * (1.0f / (AH - 1));
        const float bin_w = fmaxf(x2 - x1, 0.0f) * (1.0f / (AW - 1));
        const int i = tid / AW;
        const int j = tid - i * AW;
        const float h = y1 + (float)i * bin_h;
        const float w = x1 + (float)j * bin_w;
        const float hs = fminf(floorf(h), (float)(Hh - 2));
        const float ws = fminf(floorf(w), (float)(Ww - 2));
        const int hi = (int)fminf(fmaxf(hs, 0.0f), (float)(Hh - 2));
        const int wi = (int)fminf(fmaxf(ws, 0.0f), (float)(Ww - 2));
        const bool valid = (h >= 0.0f) && (h < (float)Hh) &&
                           (w >= 0.0f) && (w < (float)Ww);
        int4 pr;
        pr.x = hi * Ww + wi;
        pr.y = __float_as_int(h - hs);
        pr.z = __float_as_int(w - ws);
        pr.w = __float_as_int(valid ? 1.0f : 0.0f);
        s_par[tid] = pr;
        if (tid == 0) s_fbase = (int)rp[0] * (Cc * HW);
    }
    __syncthreads();

    const float* fb = feats + s_fbase + cs * (CPB * HW);
    float* ob = out + (size_t)n * (Cc * NB) + cs * OUT_PER_BLK;

    #pragma unroll 4
    for (int k = tid; k < OUT_PER_BLK; k += 256) {
        const int c  = k / NB;
        const int rr = k - c * NB;
        const int4 pr = s_par[rr];
        const float hr  = __int_as_float(pr.y);
        const float wr  = __int_as_float(pr.z);
        const float msk = __int_as_float(pr.w);
        const float* p = fb + c * HW + pr.x;
        const float v00 = p[0];
        const float v01 = p[1];
        const float v10 = p[Ww];
        const float v11 = p[Ww + 1];
        const float top = v00 + (v01 - v00) * wr;
        const float bot = v10 + (v11 - v10) * wr;
        __builtin_nontemporal_store((top + (bot - top) * hr) * msk, &ob[k]);
    }
}
// ========================================================================

extern "C" void kernel_launch(void* const* d_in, const int* in_sizes, int n_in,
                              void* d_out, int out_size, void* d_ws, size_t ws_size,
                              hipStream_t stream) {
    const float* feats = (const float*)d_in[0];
    const float* rois  = (const float*)d_in[1];
    float* out = (float*)d_out;
    int* perm = (int*)d_ws;                      // first 4096 B
    const size_t FT_BYTES = (size_t)Bb * Cc * HW * sizeof(float);  // 78.64 MB
    if (ws_size >= FT_BYTES + 4096) {
        float* ft = (float*)((char*)d_ws + 4096);
        prep_kernel<<<TBLKS + 1, 256, 0, stream>>>(feats, rois, ft, perm);
        roialign_t_kernel<<<Nn * CSPLIT, 256, 0, stream>>>(ft, rois, perm, out);
    } else {
        roi_perm_kernel<<<1, 256, 0, stream>>>(rois, perm);
        roialign_kernel<<<Nn * CSPLIT, 256, 0, stream>>>(feats, rois, perm, out);
    }
}